// Round 5
// baseline (188.098 us; speedup 1.0000x reference)
//
#include <hip/hip_runtime.h>

// Problem constants (reference: N=4, L=2048, H=16, D=32, DIM=512)
#define NB      4
#define L_SEQ   2048
#define H_HEADS 16
#define D32     32
#define DIM     512
#define NH      (NB * H_HEADS)   // 64
#define CHUNK   64
#define NCHUNK  (L_SEQ / CHUNK)  // 32

typedef __attribute__((ext_vector_type(8))) short bf16x8;
typedef __attribute__((ext_vector_type(4))) float f32x4;

// f32 -> bf16 round-to-nearest-even (inputs are finite normals)
__device__ __forceinline__ unsigned short f2bf(float x) {
    unsigned u = __float_as_uint(x);
    u += 0x7fff + ((u >> 16) & 1);
    return (unsigned short)(u >> 16);
}
__device__ __forceinline__ unsigned pack2(float lo, float hi) {
    return (unsigned)f2bf(lo) | ((unsigned)f2bf(hi) << 16);
}

// ---------------------------------------------------------------------------
// Kernel 0: f32 -> bf16 conversion of query, key, Wq, Wk, Wv into one
// contiguous bf16 region (same order). 8 elements/thread, exact cover.
// ---------------------------------------------------------------------------
#define QN  4194304           // query elems
#define WN  262144            // one weight matrix
#define TOT (2*QN + 3*WN)     // 9,175,040
__global__ __launch_bounds__(256) void convert_kernel(
    const float* __restrict__ query, const float* __restrict__ key,
    const float* __restrict__ Wq, const float* __restrict__ Wk,
    const float* __restrict__ Wv, unsigned short* __restrict__ dst)
{
    int idx = (blockIdx.x * 256 + threadIdx.x) * 8;
    const float* src; int off;
    if (idx < QN)               { src = query; off = idx; }
    else if (idx < 2*QN)        { src = key;   off = idx - QN; }
    else if (idx < 2*QN + WN)   { src = Wq;    off = idx - 2*QN; }
    else if (idx < 2*QN + 2*WN) { src = Wk;    off = idx - 2*QN - WN; }
    else                        { src = Wv;    off = idx - 2*QN - 2*WN; }
    float4 a = *(const float4*)(src + off);
    float4 b = *(const float4*)(src + off + 4);
    *(uint4*)(dst + idx) = make_uint4(pack2(a.x, a.y), pack2(a.z, a.w),
                                      pack2(b.x, b.y), pack2(b.z, b.w));
}

// ---------------------------------------------------------------------------
// Kernel 1: three GEMMs via bf16 MFMA — NO LDS, NO BARRIERS.
// Both operands are K-major bf16, so every MFMA fragment is a direct
// contiguous 16B global load (served from L2/L3). Each wave computes a
// 64x64 C tile (4x4 grid of 16x16x32 MFMA, 16 f32x4 accumulators).
//   z=0: C[l][dout] = query @ Wq^T -> softmax(heads) -> Qs [nh][l][d]
//   z=1: C[l][dout] = key   @ Wk^T -> softmax(heads) -> Ks [nh][l][d]
//   z=2: C[dout][l] = Wv @ key^T   -> Vt [nh][d][l]   (transposed compute)
// Block = 4 waves in a 2x2 grid -> 128x128 block tile; grid (4,64,3).
// ---------------------------------------------------------------------------
__global__ __launch_bounds__(256) void gemm3_mfma_kernel(
    const unsigned short* __restrict__ qb, const unsigned short* __restrict__ kb2,
    const unsigned short* __restrict__ wqb, const unsigned short* __restrict__ wkb,
    const unsigned short* __restrict__ wvb,
    unsigned short* __restrict__ Qs, unsigned short* __restrict__ Ks,
    unsigned short* __restrict__ Vt)
{
    const int z = blockIdx.z;
    const unsigned short *PA, *PB;   // PA rows = output rows(m), PB rows = cols(n)
    int m0, n0;
    if (z == 0)      { PA = qb;  PB = wqb; m0 = blockIdx.y*128; n0 = blockIdx.x*128; }
    else if (z == 1) { PA = kb2; PB = wkb; m0 = blockIdx.y*128; n0 = blockIdx.x*128; }
    else             { PA = wvb; PB = kb2; m0 = blockIdx.x*128; n0 = blockIdx.y*128; }

    const int t    = threadIdx.x;
    const int w    = t >> 6;
    const int lane = t & 63;
    const int wm   = w >> 1, wn = w & 1;
    const int lm   = lane & 15, quad = lane >> 4;

    // fragment base pointers: row = (tilebase + lm), k-offset = quad*8
    const unsigned short* pa = PA + (size_t)(m0 + wm * 64 + lm) * DIM + quad * 8;
    const unsigned short* pb = PB + (size_t)(n0 + wn * 64 + lm) * DIM + quad * 8;

    f32x4 acc[4][4] = {};

    #pragma unroll 4
    for (int kb = 0; kb < DIM; kb += 32) {
        bf16x8 af[4], bfr[4];
        #pragma unroll
        for (int i = 0; i < 4; i++)
            af[i] = *(const bf16x8*)(pa + (size_t)i * 16 * DIM + kb);
        #pragma unroll
        for (int j = 0; j < 4; j++)
            bfr[j] = *(const bf16x8*)(pb + (size_t)j * 16 * DIM + kb);
        #pragma unroll
        for (int i = 0; i < 4; i++)
            #pragma unroll
            for (int j = 0; j < 4; j++)
                acc[i][j] = __builtin_amdgcn_mfma_f32_16x16x32_bf16(
                    af[i], bfr[j], acc[i][j], 0, 0, 0);
    }

    // fused softmax over D=32 head groups along cols (Q and K only)
    if (z < 2) {
        #pragma unroll
        for (int i = 0; i < 4; i++)
            #pragma unroll
            for (int jp = 0; jp < 2; jp++)
                #pragma unroll
                for (int r = 0; r < 4; r++) {
                    float a = acc[i][2 * jp][r], b = acc[i][2 * jp + 1][r];
                    float m = fmaxf(a, b);
                    #pragma unroll
                    for (int off = 1; off < 16; off <<= 1)
                        m = fmaxf(m, __shfl_xor(m, off, 64));
                    float ea = __expf(a - m), eb = __expf(b - m);
                    float s = ea + eb;
                    #pragma unroll
                    for (int off = 1; off < 16; off <<= 1)
                        s += __shfl_xor(s, off, 64);
                    float inv = 1.0f / s;
                    acc[i][2 * jp][r]     = ea * inv;
                    acc[i][2 * jp + 1][r] = eb * inv;
                }
    }

    // epilogue: C frag row = m0+wm*64+i*16+quad*4+r, col = n0+wn*64+j*16+lm
    #pragma unroll
    for (int i = 0; i < 4; i++) {
        int rbase = m0 + wm * 64 + i * 16 + quad * 4;
        #pragma unroll
        for (int r = 0; r < 4; r++) {
            int rg = rbase + r;
            #pragma unroll
            for (int j = 0; j < 4; j++) {
                int cg = n0 + wn * 64 + j * 16 + lm;
                unsigned short val = f2bf(acc[i][j][r]);
                if (z < 2) {
                    int n = rg >> 11, l = rg & 2047;
                    int h = cg >> 5,  e = cg & 31;
                    unsigned short* dp = (z == 0) ? Qs : Ks;
                    dp[(((size_t)(n * H_HEADS + h)) * L_SEQ + l) * D32 + e] = val;
                } else {
                    int h = rg >> 5,  e = rg & 31;     // rows are dout
                    int n = cg >> 11, l = cg & 2047;   // cols are l
                    Vt[(((size_t)(n * H_HEADS + h)) * D32 + e) * L_SEQ + l] = val;
                }
            }
        }
    }
}

// ---------------------------------------------------------------------------
// Kernel 2: per-chunk KV sums via MFMA (no LDS):
//   ckvT[e][d] = sum_l V[l][e] * K[l][d]
// A-frags from Vt (vector), B-frags from Ks via 8 scalar u16 loads (lanes
// 0..15 contiguous 32B, L2-resident). One wave per (c,nh).
// ---------------------------------------------------------------------------
__global__ __launch_bounds__(256) void chunk_kv_mfma_kernel(
    const unsigned short* __restrict__ Ks, const unsigned short* __restrict__ Vt,
    float* __restrict__ ckvT)
{
    const int nh = blockIdx.y;
    const int c  = blockIdx.x * 4 + (threadIdx.x >> 6);
    const int lane = threadIdx.x & 63;
    const int lm = lane & 15, quad = lane >> 4;

    f32x4 acc[2][2] = {};
    #pragma unroll
    for (int ch = 0; ch < 2; ch++) {
        bf16x8 aV[2], bK[2];
        #pragma unroll
        for (int mt = 0; mt < 2; mt++)
            aV[mt] = *(const bf16x8*)(Vt + ((size_t)nh * D32 + mt * 16 + lm) * L_SEQ
                                         + c * CHUNK + ch * 32 + quad * 8);
        #pragma unroll
        for (int nt = 0; nt < 2; nt++) {
            const unsigned short* kp = Ks
                + ((size_t)nh * L_SEQ + c * CHUNK + ch * 32 + quad * 8) * D32
                + nt * 16 + lm;
            #pragma unroll
            for (int j = 0; j < 8; j++) bK[nt][j] = (short)kp[j * D32];
        }
        #pragma unroll
        for (int mt = 0; mt < 2; mt++)
            #pragma unroll
            for (int nt = 0; nt < 2; nt++)
                acc[mt][nt] = __builtin_amdgcn_mfma_f32_16x16x32_bf16(
                    aV[mt], bK[nt], acc[mt][nt], 0, 0, 0);
    }
    #pragma unroll
    for (int mt = 0; mt < 2; mt++)
        #pragma unroll
        for (int nt = 0; nt < 2; nt++)
            #pragma unroll
            for (int r = 0; r < 4; r++) {
                int e = mt * 16 + quad * 4 + r;
                int d = nt * 16 + lm;
                ckvT[(((size_t)nh * NCHUNK + c) * 32 + e) * 32 + d] = acc[mt][nt][r];
            }
}

// ---------------------------------------------------------------------------
// Kernel 3: exclusive prefix over 32 chunks; reads ckvT f32, writes SpT bf16.
// Batched-8 in-register scan (no spill).
// ---------------------------------------------------------------------------
__global__ __launch_bounds__(256) void prefix_kernel(
    const float* __restrict__ ckvT, unsigned short* __restrict__ SpT)
{
    int nh = blockIdx.x;
    int t  = threadIdx.x;
    const float* base = ckvT + (size_t)nh * NCHUNK * 1024 + t * 4;
    unsigned short* sp = SpT + (size_t)nh * NCHUNK * 1024 + t * 4;
    float4 acc = make_float4(0.f, 0.f, 0.f, 0.f);
    #pragma unroll
    for (int cb = 0; cb < NCHUNK; cb += 8) {
        float4 v[8];
        #pragma unroll
        for (int j = 0; j < 8; j++)
            v[j] = *(const float4*)(base + (size_t)(cb + j) * 1024);
        #pragma unroll
        for (int j = 0; j < 8; j++) {
            ushort4 u;
            u.x = f2bf(acc.x); u.y = f2bf(acc.y);
            u.z = f2bf(acc.z); u.w = f2bf(acc.w);
            *(ushort4*)(sp + (size_t)(cb + j) * 1024) = u;
            acc.x += v[j].x; acc.y += v[j].y;
            acc.z += v[j].z; acc.w += v[j].w;
        }
    }
}

// ---------------------------------------------------------------------------
// Kernel 4: per-chunk output via MFMA:
//   P = tril(Qc Kc^T)  (bf16 staged in LDS);  O = Qc·SpT^T + P·Vt^T
// ---------------------------------------------------------------------------
__global__ __launch_bounds__(256) void chunk_out_mfma_kernel(
    const unsigned short* __restrict__ Qs, const unsigned short* __restrict__ Ks,
    const unsigned short* __restrict__ Vt, const unsigned short* __restrict__ SpT,
    float* __restrict__ out)
{
    const int c = blockIdx.x, nh = blockIdx.y;
    __shared__ unsigned short P[64 * 72];   // row l, col l', stride 72

    const int t = threadIdx.x, w = t >> 6, lane = t & 63;
    const int lm = lane & 15, quad = lane >> 4;

    bf16x8 aQ = *(const bf16x8*)(Qs + ((size_t)nh * L_SEQ + c * CHUNK + w * 16 + lm) * D32
                                    + quad * 8);

    // Phase A: P tiles j=0..3 (j>w stored as zeros)
    #pragma unroll
    for (int j = 0; j < 4; j++) {
        f32x4 p = {};
        if (j <= w) {
            bf16x8 bK = *(const bf16x8*)(Ks + ((size_t)nh * L_SEQ + c * CHUNK + j * 16 + lm) * D32
                                            + quad * 8);
            p = __builtin_amdgcn_mfma_f32_16x16x32_bf16(aQ, bK, p, 0, 0, 0);
            if (j == w) {
                #pragma unroll
                for (int r = 0; r < 4; r++)
                    if (lm > quad * 4 + r) p[r] = 0.f;   // causal: keep l' <= l
            }
        }
        #pragma unroll
        for (int r = 0; r < 4; r++)
            P[(w * 16 + quad * 4 + r) * 72 + j * 16 + lm] = f2bf(p[r]);
    }
    __syncthreads();

    // Phase B
    const int chains = (w < 2) ? 1 : 2;
    bf16x8 aP[2];
    for (int ch = 0; ch < chains; ch++)
        aP[ch] = *(const bf16x8*)&P[(w * 16 + lm) * 72 + ch * 32 + quad * 8];

    const int n = nh >> 4, h = nh & 15;
    #pragma unroll
    for (int nt = 0; nt < 2; nt++) {
        bf16x8 bS = *(const bf16x8*)(SpT + (((size_t)nh * NCHUNK + c) * 32 + nt * 16 + lm) * 32
                                         + quad * 8);
        f32x4 acc = {};
        acc = __builtin_amdgcn_mfma_f32_16x16x32_bf16(aQ, bS, acc, 0, 0, 0);
        for (int ch = 0; ch < chains; ch++) {
            bf16x8 bV = *(const bf16x8*)(Vt + ((size_t)nh * D32 + nt * 16 + lm) * L_SEQ
                                            + c * CHUNK + ch * 32 + quad * 8);
            acc = __builtin_amdgcn_mfma_f32_16x16x32_bf16(aP[ch], bV, acc, 0, 0, 0);
        }
        #pragma unroll
        for (int r = 0; r < 4; r++) {
            int lg = c * CHUNK + w * 16 + quad * 4 + r;
            out[((size_t)n * L_SEQ + lg) * DIM + h * D32 + nt * 16 + lm] = acc[r];
        }
    }
}

// ---------------------------------------------------------------------------
extern "C" void kernel_launch(void* const* d_in, const int* in_sizes, int n_in,
                              void* d_out, int out_size, void* d_ws, size_t ws_size,
                              hipStream_t stream)
{
    (void)in_sizes; (void)n_in; (void)out_size; (void)ws_size;
    const float* query = (const float*)d_in[0];
    const float* key   = (const float*)d_in[1];
    const float* Wq    = (const float*)d_in[2];
    const float* Wk    = (const float*)d_in[3];
    const float* Wv    = (const float*)d_in[4];
    float* out = (float*)d_out;

    // ws layout (bf16 shorts unless noted):
    //  [qb 4.19M][kb 4.19M][wqb 256K][wkb 256K][wvb 256K]
    //  [Qs 4.19M][Ks 4.19M][Vt 4.19M][SpT 2.10M][ckvT f32 2.10M]  ~= 56 MB
    unsigned short* bf = (unsigned short*)d_ws;
    unsigned short* qb  = bf;
    unsigned short* kb  = qb + QN;
    unsigned short* wqb = kb + QN;
    unsigned short* wkb = wqb + WN;
    unsigned short* wvb = wkb + WN;
    unsigned short* Qs  = wvb + WN;
    const size_t SZ = (size_t)NH * L_SEQ * D32;
    unsigned short* Ks  = Qs + SZ;
    unsigned short* Vt  = Ks + SZ;
    unsigned short* SpT = Vt + SZ;
    float* ckvT = (float*)(SpT + (size_t)NH * NCHUNK * 1024);

    dim3 blk(256);
    convert_kernel<<<dim3(TOT / (256 * 8)), blk, 0, stream>>>(query, key, Wq, Wk, Wv, qb);
    gemm3_mfma_kernel<<<dim3(4, 64, 3), blk, 0, stream>>>(qb, kb, wqb, wkb, wvb,
                                                          Qs, Ks, Vt);
    chunk_kv_mfma_kernel<<<dim3(NCHUNK / 4, NH), blk, 0, stream>>>(Ks, Vt, ckvT);
    prefix_kernel<<<dim3(NH), blk, 0, stream>>>(ckvT, SpT);
    chunk_out_mfma_kernel<<<dim3(NCHUNK, NH), blk, 0, stream>>>(Qs, Ks, Vt, SpT, out);
}

// Round 6
// 165.980 us; speedup vs baseline: 1.1333x; 1.1333x over previous
//
#include <hip/hip_runtime.h>

// Problem constants (reference: N=4, L=2048, H=16, D=32, DIM=512)
#define NB      4
#define L_SEQ   2048
#define H_HEADS 16
#define D32     32
#define DIM     512
#define NH      (NB * H_HEADS)   // 64
#define CHUNK   64
#define NCHUNK  (L_SEQ / CHUNK)  // 32

typedef __attribute__((ext_vector_type(8))) short bf16x8;
typedef __attribute__((ext_vector_type(4))) float f32x4;

// f32 -> bf16 round-to-nearest-even (inputs are finite normals)
__device__ __forceinline__ unsigned short f2bf(float x) {
    unsigned u = __float_as_uint(x);
    u += 0x7fff + ((u >> 16) & 1);
    return (unsigned short)(u >> 16);
}
__device__ __forceinline__ unsigned pack2(float lo, float hi) {
    return (unsigned)f2bf(lo) | ((unsigned)f2bf(hi) << 16);
}

// ---------------------------------------------------------------------------
// Kernel 0: f32 -> bf16 conversion of query, key, Wq, Wk, Wv into one
// contiguous bf16 region (same order). 8 elements/thread, exact cover.
// ---------------------------------------------------------------------------
#define QN  4194304           // query elems
#define WN  262144            // one weight matrix
#define TOT (2*QN + 3*WN)     // 9,175,040
__global__ __launch_bounds__(256) void convert_kernel(
    const float* __restrict__ query, const float* __restrict__ key,
    const float* __restrict__ Wq, const float* __restrict__ Wk,
    const float* __restrict__ Wv, unsigned short* __restrict__ dst)
{
    int idx = (blockIdx.x * 256 + threadIdx.x) * 8;
    const float* src; int off;
    if (idx < QN)               { src = query; off = idx; }
    else if (idx < 2*QN)        { src = key;   off = idx - QN; }
    else if (idx < 2*QN + WN)   { src = Wq;    off = idx - 2*QN; }
    else if (idx < 2*QN + 2*WN) { src = Wk;    off = idx - 2*QN - WN; }
    else                        { src = Wv;    off = idx - 2*QN - 2*WN; }
    float4 a = *(const float4*)(src + off);
    float4 b = *(const float4*)(src + off + 4);
    *(uint4*)(dst + idx) = make_uint4(pack2(a.x, a.y), pack2(a.z, a.w),
                                      pack2(b.x, b.y), pack2(b.z, b.w));
}

// ---------------------------------------------------------------------------
// Kernel 1: three GEMMs via bf16 MFMA, LDS-staged (R3 structure) from
// pre-converted bf16 inputs — staging is a pure uint4 global->LDS copy.
//   z=0: C[l][dout] = query @ Wq^T -> softmax(heads) -> Qs [nh][l][d]
//   z=1: C[l][dout] = key   @ Wk^T -> softmax(heads) -> Ks [nh][l][d]
//   z=2: C[dout][l] = Wv @ key^T   -> Vt [nh][d][l]   (transposed compute,
//        coalesced Vt stores)
// Tile 128x128xBK32, 256 thr = 4 waves, each a 64x64 subtile. LDS tiles in
// MFMA fragment-chunk order (chunk li=row*4+kq at 16B offset li*16): both
// ds_write_b128 staging and ds_read_b128 fragment loads are conflict-free.
// ---------------------------------------------------------------------------
__global__ __launch_bounds__(256) void gemm3_mfma_kernel(
    const unsigned short* __restrict__ qb, const unsigned short* __restrict__ kb2,
    const unsigned short* __restrict__ wqb, const unsigned short* __restrict__ wkb,
    const unsigned short* __restrict__ wvb,
    unsigned short* __restrict__ Qs, unsigned short* __restrict__ Ks,
    unsigned short* __restrict__ Vt)
{
    const int z = blockIdx.z;
    const unsigned short *PA, *PB;   // PA rows = output rows(m), PB rows = cols(n)
    int m0, n0;
    if (z == 0)      { PA = qb;  PB = wqb; m0 = blockIdx.y*128; n0 = blockIdx.x*128; }
    else if (z == 1) { PA = kb2; PB = wkb; m0 = blockIdx.y*128; n0 = blockIdx.x*128; }
    else             { PA = wvb; PB = kb2; m0 = blockIdx.x*128; n0 = blockIdx.y*128; }

    __shared__ unsigned short Asm[128 * 32];   // 8 KB
    __shared__ unsigned short Bsm[128 * 32];   // 8 KB

    const int t    = threadIdx.x;
    const int w    = t >> 6;
    const int lane = t & 63;
    const int wm   = w >> 1, wn = w & 1;
    const int chunkoff = ((lane & 15) * 4 + (lane >> 4)) * 8;

    f32x4 acc[4][4] = {};

    for (int kb = 0; kb < DIM; kb += 32) {
        // stage A,B tiles: chunks li = t, t+256 per tile; pure 16B copies
        #pragma unroll
        for (int rep = 0; rep < 2; rep++) {
            int li  = t + rep * 256;
            int row = li >> 2, kq = li & 3;
            uint4 av = *(const uint4*)(PA + (size_t)(m0 + row) * DIM + kb + kq * 8);
            uint4 bv = *(const uint4*)(PB + (size_t)(n0 + row) * DIM + kb + kq * 8);
            ((uint4*)Asm)[li] = av;
            ((uint4*)Bsm)[li] = bv;
        }
        __syncthreads();

        bf16x8 af[4], bfr[4];
        #pragma unroll
        for (int i = 0; i < 4; i++)
            af[i] = *(const bf16x8*)(Asm + (wm * 4 + i) * 512 + chunkoff);
        #pragma unroll
        for (int j = 0; j < 4; j++)
            bfr[j] = *(const bf16x8*)(Bsm + (wn * 4 + j) * 512 + chunkoff);
        #pragma unroll
        for (int i = 0; i < 4; i++)
            #pragma unroll
            for (int j = 0; j < 4; j++)
                acc[i][j] = __builtin_amdgcn_mfma_f32_16x16x32_bf16(
                    af[i], bfr[j], acc[i][j], 0, 0, 0);
        __syncthreads();
    }

    // fused softmax over D=32 head groups along cols (Q and K only)
    if (z < 2) {
        #pragma unroll
        for (int i = 0; i < 4; i++)
            #pragma unroll
            for (int jp = 0; jp < 2; jp++)
                #pragma unroll
                for (int r = 0; r < 4; r++) {
                    float a = acc[i][2 * jp][r], b = acc[i][2 * jp + 1][r];
                    float m = fmaxf(a, b);
                    #pragma unroll
                    for (int off = 1; off < 16; off <<= 1)
                        m = fmaxf(m, __shfl_xor(m, off, 64));
                    float ea = __expf(a - m), eb = __expf(b - m);
                    float s = ea + eb;
                    #pragma unroll
                    for (int off = 1; off < 16; off <<= 1)
                        s += __shfl_xor(s, off, 64);
                    float inv = 1.0f / s;
                    acc[i][2 * jp][r]     = ea * inv;
                    acc[i][2 * jp + 1][r] = eb * inv;
                }
    }

    // epilogue: C frag row = m0+wm*64+i*16+quad*4+r, col = n0+wn*64+j*16+lm
    const int quad = lane >> 4, lm = lane & 15;
    #pragma unroll
    for (int i = 0; i < 4; i++) {
        int rbase = m0 + wm * 64 + i * 16 + quad * 4;
        #pragma unroll
        for (int r = 0; r < 4; r++) {
            int rg = rbase + r;
            #pragma unroll
            for (int j = 0; j < 4; j++) {
                int cg = n0 + wn * 64 + j * 16 + lm;
                unsigned short val = f2bf(acc[i][j][r]);
                if (z < 2) {
                    int n = rg >> 11, l = rg & 2047;
                    int h = cg >> 5,  e = cg & 31;
                    unsigned short* dp = (z == 0) ? Qs : Ks;
                    dp[(((size_t)(n * H_HEADS + h)) * L_SEQ + l) * D32 + e] = val;
                } else {
                    int h = rg >> 5,  e = rg & 31;     // rows are dout
                    int n = cg >> 11, l = cg & 2047;   // cols are l
                    Vt[(((size_t)(n * H_HEADS + h)) * D32 + e) * L_SEQ + l] = val;
                }
            }
        }
    }
}

// ---------------------------------------------------------------------------
// Kernel 2: per-chunk KV sums via MFMA:
//   ckvT[e][d] = sum_l V[l][e] * K[l][d]
// A-frags from Vt (vector global). K is only available l-major (Ks), so the
// block stages its 4 chunks of K into LDS (row stride 36 shorts -> quad
// reads alias 2-way only, which is free) and reads d-major B-frags from LDS.
// One wave per (c,nh); block = 4 consecutive chunks of one nh.
// ---------------------------------------------------------------------------
__global__ __launch_bounds__(256) void chunk_kv_mfma_kernel(
    const unsigned short* __restrict__ Ks, const unsigned short* __restrict__ Vt,
    float* __restrict__ ckvT)
{
    const int nh = blockIdx.y;
    const int t  = threadIdx.x;
    const int w  = t >> 6;
    const int c  = blockIdx.x * 4 + w;
    const int lane = t & 63;
    const int lm = lane & 15, quad = lane >> 4;

    __shared__ unsigned short Kl[4 * 64 * 36];   // 18 KB, row stride 36

    // stage 4 chunks (4*64 rows x 32 d) of K: 1024 16B-chunks, 4 per thread
    {
        const unsigned short* kg = Ks + ((size_t)nh * L_SEQ + blockIdx.x * 4 * CHUNK) * D32;
        #pragma unroll
        for (int rr = 0; rr < 4; rr++) {
            int gi = t + rr * 256;          // global 16B-chunk index
            int lrow = gi >> 2, kq = gi & 3;
            uint4 v = *(const uint4*)(kg + (size_t)lrow * D32 + kq * 8);
            *(uint4*)(Kl + lrow * 36 + kq * 8) = v;
        }
    }
    __syncthreads();

    f32x4 acc[2][2] = {};
    #pragma unroll
    for (int ch = 0; ch < 2; ch++) {
        bf16x8 aV[2], bK[2];
        #pragma unroll
        for (int mt = 0; mt < 2; mt++)
            aV[mt] = *(const bf16x8*)(Vt + ((size_t)nh * D32 + mt * 16 + lm) * L_SEQ
                                         + c * CHUNK + ch * 32 + quad * 8);
        #pragma unroll
        for (int nt = 0; nt < 2; nt++) {
            const unsigned short* kp = Kl + (w * 64 + ch * 32 + quad * 8) * 36
                                          + nt * 16 + lm;
            #pragma unroll
            for (int j = 0; j < 8; j++) bK[nt][j] = (short)kp[j * 36];
        }
        #pragma unroll
        for (int mt = 0; mt < 2; mt++)
            #pragma unroll
            for (int nt = 0; nt < 2; nt++)
                acc[mt][nt] = __builtin_amdgcn_mfma_f32_16x16x32_bf16(
                    aV[mt], bK[nt], acc[mt][nt], 0, 0, 0);
    }
    #pragma unroll
    for (int mt = 0; mt < 2; mt++)
        #pragma unroll
        for (int nt = 0; nt < 2; nt++)
            #pragma unroll
            for (int r = 0; r < 4; r++) {
                int e = mt * 16 + quad * 4 + r;
                int d = nt * 16 + lm;
                ckvT[(((size_t)nh * NCHUNK + c) * 32 + e) * 32 + d] = acc[mt][nt][r];
            }
}

// ---------------------------------------------------------------------------
// Kernel 3: exclusive prefix over 32 chunks; reads ckvT f32, writes SpT bf16.
// Batched-8 in-register scan (no spill).
// ---------------------------------------------------------------------------
__global__ __launch_bounds__(256) void prefix_kernel(
    const float* __restrict__ ckvT, unsigned short* __restrict__ SpT)
{
    int nh = blockIdx.x;
    int t  = threadIdx.x;
    const float* base = ckvT + (size_t)nh * NCHUNK * 1024 + t * 4;
    unsigned short* sp = SpT + (size_t)nh * NCHUNK * 1024 + t * 4;
    float4 acc = make_float4(0.f, 0.f, 0.f, 0.f);
    #pragma unroll
    for (int cb = 0; cb < NCHUNK; cb += 8) {
        float4 v[8];
        #pragma unroll
        for (int j = 0; j < 8; j++)
            v[j] = *(const float4*)(base + (size_t)(cb + j) * 1024);
        #pragma unroll
        for (int j = 0; j < 8; j++) {
            ushort4 u;
            u.x = f2bf(acc.x); u.y = f2bf(acc.y);
            u.z = f2bf(acc.z); u.w = f2bf(acc.w);
            *(ushort4*)(sp + (size_t)(cb + j) * 1024) = u;
            acc.x += v[j].x; acc.y += v[j].y;
            acc.z += v[j].z; acc.w += v[j].w;
        }
    }
}

// ---------------------------------------------------------------------------
// Kernel 4: per-chunk output via MFMA:
//   P = tril(Qc Kc^T)  (bf16 staged in LDS);  O = Qc·SpT^T + P·Vt^T
// ---------------------------------------------------------------------------
__global__ __launch_bounds__(256) void chunk_out_mfma_kernel(
    const unsigned short* __restrict__ Qs, const unsigned short* __restrict__ Ks,
    const unsigned short* __restrict__ Vt, const unsigned short* __restrict__ SpT,
    float* __restrict__ out)
{
    const int c = blockIdx.x, nh = blockIdx.y;
    __shared__ unsigned short P[64 * 72];   // row l, col l', stride 72

    const int t = threadIdx.x, w = t >> 6, lane = t & 63;
    const int lm = lane & 15, quad = lane >> 4;

    bf16x8 aQ = *(const bf16x8*)(Qs + ((size_t)nh * L_SEQ + c * CHUNK + w * 16 + lm) * D32
                                    + quad * 8);

    // Phase A: P tiles j=0..3 (j>w stored as zeros)
    #pragma unroll
    for (int j = 0; j < 4; j++) {
        f32x4 p = {};
        if (j <= w) {
            bf16x8 bK = *(const bf16x8*)(Ks + ((size_t)nh * L_SEQ + c * CHUNK + j * 16 + lm) * D32
                                            + quad * 8);
            p = __builtin_amdgcn_mfma_f32_16x16x32_bf16(aQ, bK, p, 0, 0, 0);
            if (j == w) {
                #pragma unroll
                for (int r = 0; r < 4; r++)
                    if (lm > quad * 4 + r) p[r] = 0.f;   // causal: keep l' <= l
            }
        }
        #pragma unroll
        for (int r = 0; r < 4; r++)
            P[(w * 16 + quad * 4 + r) * 72 + j * 16 + lm] = f2bf(p[r]);
    }
    __syncthreads();

    // Phase B
    const int chains = (w < 2) ? 1 : 2;
    bf16x8 aP[2];
    for (int ch = 0; ch < chains; ch++)
        aP[ch] = *(const bf16x8*)&P[(w * 16 + lm) * 72 + ch * 32 + quad * 8];

    const int n = nh >> 4, h = nh & 15;
    #pragma unroll
    for (int nt = 0; nt < 2; nt++) {
        bf16x8 bS = *(const bf16x8*)(SpT + (((size_t)nh * NCHUNK + c) * 32 + nt * 16 + lm) * 32
                                         + quad * 8);
        f32x4 acc = {};
        acc = __builtin_amdgcn_mfma_f32_16x16x32_bf16(aQ, bS, acc, 0, 0, 0);
        for (int ch = 0; ch < chains; ch++) {
            bf16x8 bV = *(const bf16x8*)(Vt + ((size_t)nh * D32 + nt * 16 + lm) * L_SEQ
                                            + c * CHUNK + ch * 32 + quad * 8);
            acc = __builtin_amdgcn_mfma_f32_16x16x32_bf16(aP[ch], bV, acc, 0, 0, 0);
        }
        #pragma unroll
        for (int r = 0; r < 4; r++) {
            int lg = c * CHUNK + w * 16 + quad * 4 + r;
            out[((size_t)n * L_SEQ + lg) * DIM + h * D32 + nt * 16 + lm] = acc[r];
        }
    }
}

// ---------------------------------------------------------------------------
extern "C" void kernel_launch(void* const* d_in, const int* in_sizes, int n_in,
                              void* d_out, int out_size, void* d_ws, size_t ws_size,
                              hipStream_t stream)
{
    (void)in_sizes; (void)n_in; (void)out_size; (void)ws_size;
    const float* query = (const float*)d_in[0];
    const float* key   = (const float*)d_in[1];
    const float* Wq    = (const float*)d_in[2];
    const float* Wk    = (const float*)d_in[3];
    const float* Wv    = (const float*)d_in[4];
    float* out = (float*)d_out;

    // ws layout (bf16 shorts unless noted):
    //  [qb 4.19M][kb 4.19M][wqb 256K][wkb 256K][wvb 256K]
    //  [Qs 4.19M][Ks 4.19M][Vt 4.19M][SpT 2.10M][ckvT f32 2.10M]  ~= 56 MB
    unsigned short* bf = (unsigned short*)d_ws;
    unsigned short* qb  = bf;
    unsigned short* kb  = qb + QN;
    unsigned short* wqb = kb + QN;
    unsigned short* wkb = wqb + WN;
    unsigned short* wvb = wkb + WN;
    unsigned short* Qs  = wvb + WN;
    const size_t SZ = (size_t)NH * L_SEQ * D32;
    unsigned short* Ks  = Qs + SZ;
    unsigned short* Vt  = Ks + SZ;
    unsigned short* SpT = Vt + SZ;
    float* ckvT = (float*)(SpT + (size_t)NH * NCHUNK * 1024);

    dim3 blk(256);
    convert_kernel<<<dim3(TOT / (256 * 8)), blk, 0, stream>>>(query, key, Wq, Wk, Wv, qb);
    gemm3_mfma_kernel<<<dim3(4, 64, 3), blk, 0, stream>>>(qb, kb, wqb, wkb, wvb,
                                                          Qs, Ks, Vt);
    chunk_kv_mfma_kernel<<<dim3(NCHUNK / 4, NH), blk, 0, stream>>>(Ks, Vt, ckvT);
    prefix_kernel<<<dim3(NH), blk, 0, stream>>>(ckvT, SpT);
    chunk_out_mfma_kernel<<<dim3(NCHUNK, NH), blk, 0, stream>>>(Qs, Ks, Vt, SpT, out);
}

// Round 7
// 140.784 us; speedup vs baseline: 1.3361x; 1.1790x over previous
//
#include <hip/hip_runtime.h>

// Problem constants (reference: N=4, L=2048, H=16, D=32, DIM=512)
#define NB      4
#define L_SEQ   2048
#define H_HEADS 16
#define D32     32
#define DIM     512
#define NH      (NB * H_HEADS)   // 64
#define CHUNK   64
#define NCHUNK  (L_SEQ / CHUNK)  // 32

typedef __attribute__((ext_vector_type(8))) short bf16x8;
typedef __attribute__((ext_vector_type(4))) float f32x4;

// f32 -> bf16 round-to-nearest-even (inputs are finite normals)
__device__ __forceinline__ unsigned short f2bf(float x) {
    unsigned u = __float_as_uint(x);
    u += 0x7fff + ((u >> 16) & 1);
    return (unsigned short)(u >> 16);
}
__device__ __forceinline__ unsigned pack2(float lo, float hi) {
    return (unsigned)f2bf(lo) | ((unsigned)f2bf(hi) << 16);
}

// ---------------------------------------------------------------------------
// Kernel 0: f32 -> bf16 conversion of query, key, Wq, Wk, Wv into one
// contiguous bf16 region (same order). 8 elements/thread, exact cover.
// ---------------------------------------------------------------------------
#define QN  4194304           // query elems
#define WN  262144            // one weight matrix
#define TOT (2*QN + 3*WN)     // 9,175,040
__global__ __launch_bounds__(256) void convert_kernel(
    const float* __restrict__ query, const float* __restrict__ key,
    const float* __restrict__ Wq, const float* __restrict__ Wk,
    const float* __restrict__ Wv, unsigned short* __restrict__ dst)
{
    int idx = (blockIdx.x * 256 + threadIdx.x) * 8;
    const float* src; int off;
    if (idx < QN)               { src = query; off = idx; }
    else if (idx < 2*QN)        { src = key;   off = idx - QN; }
    else if (idx < 2*QN + WN)   { src = Wq;    off = idx - 2*QN; }
    else if (idx < 2*QN + 2*WN) { src = Wk;    off = idx - 2*QN - WN; }
    else                        { src = Wv;    off = idx - 2*QN - 2*WN; }
    float4 a = *(const float4*)(src + off);
    float4 b = *(const float4*)(src + off + 4);
    *(uint4*)(dst + idx) = make_uint4(pack2(a.x, a.y), pack2(a.z, a.w),
                                      pack2(b.x, b.y), pack2(b.z, b.w));
}

// ---------------------------------------------------------------------------
// Kernel 1: three GEMMs via bf16 MFMA, LDS-staged, fused over blockIdx.z.
//   z=0: C[l][dout] = query @ Wq^T -> softmax(heads) -> Qs [nh][l][d]
//   z=1: C[l][dout] = key   @ Wk^T -> softmax(heads) -> Ks [nh][l][d]
//   z=2: C[dout][l] = Wv @ key^T   -> Vt [nh][d][l]   (transposed compute)
// Grid (256,1,3) with XCD swizzle: bx = lin>>6 (col-tile), by = lin&63
// (row-tile). The 4 blocks sharing an A-stripe are 64 apart in dispatch
// order (64 % 8 == 0) -> same XCD -> A re-reads hit that XCD's L2.
// ---------------------------------------------------------------------------
__global__ __launch_bounds__(256) void gemm3_mfma_kernel(
    const unsigned short* __restrict__ qb, const unsigned short* __restrict__ kb2,
    const unsigned short* __restrict__ wqb, const unsigned short* __restrict__ wkb,
    const unsigned short* __restrict__ wvb,
    unsigned short* __restrict__ Qs, unsigned short* __restrict__ Ks,
    unsigned short* __restrict__ Vt)
{
    const int z  = blockIdx.z;
    const int bx = blockIdx.x >> 6;      // 0..3  (128-col tile)
    const int by = blockIdx.x & 63;      // 0..63 (128-row tile)
    const unsigned short *PA, *PB;   // PA rows = output rows(m), PB rows = cols(n)
    int m0, n0;
    if (z == 0)      { PA = qb;  PB = wqb; m0 = by*128; n0 = bx*128; }
    else if (z == 1) { PA = kb2; PB = wkb; m0 = by*128; n0 = bx*128; }
    else             { PA = wvb; PB = kb2; m0 = bx*128; n0 = by*128; }

    __shared__ unsigned short Asm[128 * 32];   // 8 KB
    __shared__ unsigned short Bsm[128 * 32];   // 8 KB

    const int t    = threadIdx.x;
    const int w    = t >> 6;
    const int lane = t & 63;
    const int wm   = w >> 1, wn = w & 1;
    const int chunkoff = ((lane & 15) * 4 + (lane >> 4)) * 8;

    f32x4 acc[4][4] = {};

    for (int kb = 0; kb < DIM; kb += 32) {
        // stage A,B tiles: chunks li = t, t+256 per tile; pure 16B copies
        #pragma unroll
        for (int rep = 0; rep < 2; rep++) {
            int li  = t + rep * 256;
            int row = li >> 2, kq = li & 3;
            uint4 av = *(const uint4*)(PA + (size_t)(m0 + row) * DIM + kb + kq * 8);
            uint4 bv = *(const uint4*)(PB + (size_t)(n0 + row) * DIM + kb + kq * 8);
            ((uint4*)Asm)[li] = av;
            ((uint4*)Bsm)[li] = bv;
        }
        __syncthreads();

        bf16x8 af[4], bfr[4];
        #pragma unroll
        for (int i = 0; i < 4; i++)
            af[i] = *(const bf16x8*)(Asm + (wm * 4 + i) * 512 + chunkoff);
        #pragma unroll
        for (int j = 0; j < 4; j++)
            bfr[j] = *(const bf16x8*)(Bsm + (wn * 4 + j) * 512 + chunkoff);
        #pragma unroll
        for (int i = 0; i < 4; i++)
            #pragma unroll
            for (int j = 0; j < 4; j++)
                acc[i][j] = __builtin_amdgcn_mfma_f32_16x16x32_bf16(
                    af[i], bfr[j], acc[i][j], 0, 0, 0);
        __syncthreads();
    }

    // fused softmax over D=32 head groups along cols (Q and K only)
    if (z < 2) {
        #pragma unroll
        for (int i = 0; i < 4; i++)
            #pragma unroll
            for (int jp = 0; jp < 2; jp++)
                #pragma unroll
                for (int r = 0; r < 4; r++) {
                    float a = acc[i][2 * jp][r], b = acc[i][2 * jp + 1][r];
                    float m = fmaxf(a, b);
                    #pragma unroll
                    for (int off = 1; off < 16; off <<= 1)
                        m = fmaxf(m, __shfl_xor(m, off, 64));
                    float ea = __expf(a - m), eb = __expf(b - m);
                    float s = ea + eb;
                    #pragma unroll
                    for (int off = 1; off < 16; off <<= 1)
                        s += __shfl_xor(s, off, 64);
                    float inv = 1.0f / s;
                    acc[i][2 * jp][r]     = ea * inv;
                    acc[i][2 * jp + 1][r] = eb * inv;
                }
    }

    // epilogue: C frag row = m0+wm*64+i*16+quad*4+r, col = n0+wn*64+j*16+lm
    const int quad = lane >> 4, lm = lane & 15;
    #pragma unroll
    for (int i = 0; i < 4; i++) {
        int rbase = m0 + wm * 64 + i * 16 + quad * 4;
        #pragma unroll
        for (int r = 0; r < 4; r++) {
            int rg = rbase + r;
            #pragma unroll
            for (int j = 0; j < 4; j++) {
                int cg = n0 + wn * 64 + j * 16 + lm;
                unsigned short val = f2bf(acc[i][j][r]);
                if (z < 2) {
                    int n = rg >> 11, l = rg & 2047;
                    int h = cg >> 5,  e = cg & 31;
                    unsigned short* dp = (z == 0) ? Qs : Ks;
                    dp[(((size_t)(n * H_HEADS + h)) * L_SEQ + l) * D32 + e] = val;
                } else {
                    int h = rg >> 5,  e = rg & 31;     // rows are dout
                    int n = cg >> 11, l = cg & 2047;   // cols are l
                    Vt[(((size_t)(n * H_HEADS + h)) * D32 + e) * L_SEQ + l] = val;
                }
            }
        }
    }
}

// ---------------------------------------------------------------------------
// Kernel 2: per-chunk KV sums via MFMA — ONE WAVE PER CHUNK (64-thr blocks).
//   ckvT[e][d] = sum_l V[l][e] * K[l][d]
// Wave stages its chunk's K into a private LDS transpose buffer (stride 36),
// then 8 MFMAs. No inter-wave coupling; 2048 blocks.
// ---------------------------------------------------------------------------
__global__ __launch_bounds__(64) void chunk_kv_mfma_kernel(
    const unsigned short* __restrict__ Ks, const unsigned short* __restrict__ Vt,
    float* __restrict__ ckvT)
{
    const int c = blockIdx.x, nh = blockIdx.y;
    const int lane = threadIdx.x;
    const int lm = lane & 15, quad = lane >> 4;

    __shared__ unsigned short Kl[64 * 36];   // 4.5 KB

    // stage: lane loads its row (64B contiguous) -> padded LDS row
    {
        const unsigned short* kg = Ks + ((size_t)nh * L_SEQ + c * CHUNK + lane) * D32;
        #pragma unroll
        for (int i = 0; i < 4; i++) {
            uint4 v = *(const uint4*)(kg + i * 8);
            *(uint4*)(Kl + lane * 36 + i * 8) = v;
        }
    }
    __syncthreads();   // single wave: cheap; orders LDS writes before reads

    f32x4 acc[2][2] = {};
    #pragma unroll
    for (int ch = 0; ch < 2; ch++) {
        bf16x8 aV[2], bK[2];
        #pragma unroll
        for (int mt = 0; mt < 2; mt++)
            aV[mt] = *(const bf16x8*)(Vt + ((size_t)nh * D32 + mt * 16 + lm) * L_SEQ
                                         + c * CHUNK + ch * 32 + quad * 8);
        #pragma unroll
        for (int nt = 0; nt < 2; nt++) {
            const unsigned short* kp = Kl + (ch * 32 + quad * 8) * 36 + nt * 16 + lm;
            #pragma unroll
            for (int j = 0; j < 8; j++) bK[nt][j] = (short)kp[j * 36];
        }
        #pragma unroll
        for (int mt = 0; mt < 2; mt++)
            #pragma unroll
            for (int nt = 0; nt < 2; nt++)
                acc[mt][nt] = __builtin_amdgcn_mfma_f32_16x16x32_bf16(
                    aV[mt], bK[nt], acc[mt][nt], 0, 0, 0);
    }
    #pragma unroll
    for (int mt = 0; mt < 2; mt++)
        #pragma unroll
        for (int nt = 0; nt < 2; nt++)
            #pragma unroll
            for (int r = 0; r < 4; r++) {
                int e = mt * 16 + quad * 4 + r;
                int d = nt * 16 + lm;
                ckvT[(((size_t)nh * NCHUNK + c) * 32 + e) * 32 + d] = acc[mt][nt][r];
            }
}

// ---------------------------------------------------------------------------
// Kernel 3: exclusive prefix over 32 chunks; reads ckvT f32, writes SpT bf16.
// Grid (4, NH), 64 threads: block handles 64 of the 256 float4 slots.
// ---------------------------------------------------------------------------
__global__ __launch_bounds__(64) void prefix_kernel(
    const float* __restrict__ ckvT, unsigned short* __restrict__ SpT)
{
    int nh   = blockIdx.y;
    int slot = blockIdx.x * 64 + threadIdx.x;   // 0..255
    const float* base = ckvT + (size_t)nh * NCHUNK * 1024 + slot * 4;
    unsigned short* sp = SpT + (size_t)nh * NCHUNK * 1024 + slot * 4;
    float4 acc = make_float4(0.f, 0.f, 0.f, 0.f);
    #pragma unroll
    for (int cb = 0; cb < NCHUNK; cb += 8) {
        float4 v[8];
        #pragma unroll
        for (int j = 0; j < 8; j++)
            v[j] = *(const float4*)(base + (size_t)(cb + j) * 1024);
        #pragma unroll
        for (int j = 0; j < 8; j++) {
            ushort4 u;
            u.x = f2bf(acc.x); u.y = f2bf(acc.y);
            u.z = f2bf(acc.z); u.w = f2bf(acc.w);
            *(ushort4*)(sp + (size_t)(cb + j) * 1024) = u;
            acc.x += v[j].x; acc.y += v[j].y;
            acc.z += v[j].z; acc.w += v[j].w;
        }
    }
}

// ---------------------------------------------------------------------------
// Kernel 4: per-chunk output via MFMA — ONE WAVE PER CHUNK (64-thr blocks).
//   P = tril(Qc Kc^T) (bf16, private LDS);  O = Qc·SpT^T + P·Vt^T
// Wave owns all 4 row-tiles: 10 + 20 MFMAs, ~14 vector frag loads -> high ILP.
// ---------------------------------------------------------------------------
__global__ __launch_bounds__(64) void chunk_out_mfma_kernel(
    const unsigned short* __restrict__ Qs, const unsigned short* __restrict__ Ks,
    const unsigned short* __restrict__ Vt, const unsigned short* __restrict__ SpT,
    float* __restrict__ out)
{
    const int c = blockIdx.x, nh = blockIdx.y;
    __shared__ unsigned short P[64 * 72];   // row l, col l', stride 72 (9 KB)

    const int lane = threadIdx.x;
    const int lm = lane & 15, quad = lane >> 4;

    // A-frags of Q and B-frags of K for all 4 tiles
    bf16x8 aQ[4], bK[4];
    #pragma unroll
    for (int i = 0; i < 4; i++)
        aQ[i] = *(const bf16x8*)(Qs + ((size_t)nh * L_SEQ + c * CHUNK + i * 16 + lm) * D32
                                    + quad * 8);
    #pragma unroll
    for (int j = 0; j < 4; j++)
        bK[j] = *(const bf16x8*)(Ks + ((size_t)nh * L_SEQ + c * CHUNK + j * 16 + lm) * D32
                                    + quad * 8);

    // Phase A: P[i][j] tiles; upper (j>i) zero-filled
    #pragma unroll
    for (int i = 0; i < 4; i++) {
        #pragma unroll
        for (int j = 0; j < 4; j++) {
            f32x4 p = {};
            if (j <= i) {
                p = __builtin_amdgcn_mfma_f32_16x16x32_bf16(aQ[i], bK[j], p, 0, 0, 0);
                if (j == i) {
                    #pragma unroll
                    for (int r = 0; r < 4; r++)
                        if (lm > quad * 4 + r) p[r] = 0.f;   // causal: keep l' <= l
                }
            }
            #pragma unroll
            for (int r = 0; r < 4; r++)
                P[(i * 16 + quad * 4 + r) * 72 + j * 16 + lm] = f2bf(p[r]);
        }
    }
    __syncthreads();   // single wave: orders LDS writes before reads

    // preload phase-B global frags
    bf16x8 bS[2], bV[2][2];
    #pragma unroll
    for (int nt = 0; nt < 2; nt++) {
        bS[nt] = *(const bf16x8*)(SpT + (((size_t)nh * NCHUNK + c) * 32 + nt * 16 + lm) * 32
                                      + quad * 8);
        #pragma unroll
        for (int ch = 0; ch < 2; ch++)
            bV[nt][ch] = *(const bf16x8*)(Vt + ((size_t)nh * D32 + nt * 16 + lm) * L_SEQ
                                             + c * CHUNK + ch * 32 + quad * 8);
    }

    const int n = nh >> 4, h = nh & 15;
    #pragma unroll
    for (int i = 0; i < 4; i++) {
        const int chmax = (i >> 1) + 1;   // tiles of lp needed: i<2 -> 1, else 2
        bf16x8 aP[2];
        for (int ch = 0; ch < chmax; ch++)
            aP[ch] = *(const bf16x8*)&P[(i * 16 + lm) * 72 + ch * 32 + quad * 8];
        #pragma unroll
        for (int nt = 0; nt < 2; nt++) {
            f32x4 acc = {};
            acc = __builtin_amdgcn_mfma_f32_16x16x32_bf16(aQ[i], bS[nt], acc, 0, 0, 0);
            for (int ch = 0; ch < chmax; ch++)
                acc = __builtin_amdgcn_mfma_f32_16x16x32_bf16(aP[ch], bV[nt][ch], acc, 0, 0, 0);
            #pragma unroll
            for (int r = 0; r < 4; r++) {
                int lg = c * CHUNK + i * 16 + quad * 4 + r;
                out[((size_t)n * L_SEQ + lg) * DIM + h * D32 + nt * 16 + lm] = acc[r];
            }
        }
    }
}

// ---------------------------------------------------------------------------
extern "C" void kernel_launch(void* const* d_in, const int* in_sizes, int n_in,
                              void* d_out, int out_size, void* d_ws, size_t ws_size,
                              hipStream_t stream)
{
    (void)in_sizes; (void)n_in; (void)out_size; (void)ws_size;
    const float* query = (const float*)d_in[0];
    const float* key   = (const float*)d_in[1];
    const float* Wq    = (const float*)d_in[2];
    const float* Wk    = (const float*)d_in[3];
    const float* Wv    = (const float*)d_in[4];
    float* out = (float*)d_out;

    // ws layout (bf16 shorts unless noted):
    //  [qb 4.19M][kb 4.19M][wqb 256K][wkb 256K][wvb 256K]
    //  [Qs 4.19M][Ks 4.19M][Vt 4.19M][SpT 2.10M][ckvT f32 2.10M]  ~= 56 MB
    unsigned short* bf = (unsigned short*)d_ws;
    unsigned short* qb  = bf;
    unsigned short* kb  = qb + QN;
    unsigned short* wqb = kb + QN;
    unsigned short* wkb = wqb + WN;
    unsigned short* wvb = wkb + WN;
    unsigned short* Qs  = wvb + WN;
    const size_t SZ = (size_t)NH * L_SEQ * D32;
    unsigned short* Ks  = Qs + SZ;
    unsigned short* Vt  = Ks + SZ;
    unsigned short* SpT = Vt + SZ;
    float* ckvT = (float*)(SpT + (size_t)NH * NCHUNK * 1024);

    convert_kernel<<<dim3(TOT / (256 * 8)), dim3(256), 0, stream>>>(
        query, key, Wq, Wk, Wv, qb);
    gemm3_mfma_kernel<<<dim3(256, 1, 3), dim3(256), 0, stream>>>(
        qb, kb, wqb, wkb, wvb, Qs, Ks, Vt);
    chunk_kv_mfma_kernel<<<dim3(NCHUNK, NH), dim3(64), 0, stream>>>(Ks, Vt, ckvT);
    prefix_kernel<<<dim3(4, NH), dim3(64), 0, stream>>>(ckvT, SpT);
    chunk_out_mfma_kernel<<<dim3(NCHUNK, NH), dim3(64), 0, stream>>>(Qs, Ks, Vt, SpT, out);
}